// Round 9
// baseline (343.339 us; speedup 1.0000x reference)
//
#include <hip/hip_runtime.h>
#include <hip/hip_bf16.h>

typedef __hip_bfloat16 bf16;
typedef unsigned short ushort;

#define NN 100000
#define NE 1600000
#define NBKT 782      // ceil(NN/128) buckets of 128 dst nodes
#define BCAP 4096     // per-bucket slot capacity (mean 2046, +45 sigma)
#define EPB 8192      // edges per pass-1 block
#define NP1 196       // ceil(NE/EPB)
#define NMT 6250      // NN/16 M-tiles for the MFMA GEMM

typedef __attribute__((ext_vector_type(8))) short s8v;   // 8 bf16 (4 VGPRs)
typedef __attribute__((ext_vector_type(4))) float f4v;   // MFMA C/D

// ---- flag-dispatched load/store: flag==1 -> f32 storage, 0 -> bf16 -------
__device__ __forceinline__ float ldf(const void* p, int i, int f32) {
    return f32 ? ((const float*)p)[i] : __bfloat162float(((const bf16*)p)[i]);
}
__device__ __forceinline__ void stf(void* p, int i, int f32, float v) {
    if (f32) ((float*)p)[i] = v;
    else     ((bf16*)p)[i] = __float2bfloat16(v);
}

// round-to-nearest-even float -> bf16 bits, and back
__device__ __forceinline__ ushort f2b(float f) {
    unsigned u = __builtin_bit_cast(unsigned, f);
    u += 0x7FFF + ((u >> 16) & 1);
    return (ushort)(u >> 16);
}
__device__ __forceinline__ float b2f(ushort h) {
    unsigned u = ((unsigned)h) << 16;
    return __builtin_bit_cast(float, u);
}

// ---- dtype detection on x ~ N(0,1): byte1 of each 32b word --------------
__global__ void k_detect(const unsigned* __restrict__ x, int* __restrict__ flag) {
    __shared__ int cnt[256];
    int t = threadIdx.x, c = 0;
    for (int i = t; i < 2048; i += 256) {
        unsigned e7 = (x[i] >> 8) & 0x7F;
        c += (e7 >= 60 && e7 <= 66) ? 1 : 0;
    }
    cnt[t] = c;
    __syncthreads();
    for (int s = 128; s > 0; s >>= 1) {
        if (t < s) cnt[t] += cnt[t + s];
        __syncthreads();
    }
    if (t == 0) *flag = (cnt[0] >= 1024) ? 0 : 1;  // 1 = float32 tensors
}

__global__ void k_sentinel(unsigned* out) {
    if (threadIdx.x == 0 && blockIdx.x == 0) out[0] = 0x461C461Cu;
}

__global__ void k_zero_i(int* __restrict__ p, int n) {
    int i = blockIdx.x * 256 + threadIdx.x;
    if (i < n) p[i] = 0;
}

// zero the sentinel row NN of bufA (gather target for masked OOB slots)
__global__ void k_zero_row(bf16* __restrict__ p) {
    p[NN * 64 + threadIdx.x] = __float2bfloat16(0.f);
}

// ---------------- CSR build pass 1: bucket edges by dst>>7 ----------------
__global__ void k_pass1(const int* __restrict__ src, const int* __restrict__ dst,
                        int* __restrict__ gcur, unsigned* __restrict__ bbuf) {
    __shared__ int hist[NBKT];
    __shared__ int base[NBKT];
    int t = threadIdx.x;
    int e0 = blockIdx.x * EPB;
    for (int i = t; i < NBKT; i += 256) hist[i] = 0;
    __syncthreads();
    for (int k = 0; k < EPB; k += 256) {
        int e = e0 + k + t;
        if (e < NE) atomicAdd(&hist[dst[e] >> 7], 1);
    }
    __syncthreads();
    for (int i = t; i < NBKT; i += 256) {
        int c = hist[i];
        base[i] = c ? atomicAdd(&gcur[i], c) : 0;
    }
    __syncthreads();
    for (int i = t; i < NBKT; i += 256) hist[i] = 0;  // reuse as local cursor
    __syncthreads();
    for (int k = 0; k < EPB; k += 256) {
        int e = e0 + k + t;
        if (e < NE) {
            int d = dst[e];
            int b = d >> 7;
            int lp = atomicAdd(&hist[b], 1);
            bbuf[b * BCAP + base[b] + lp] = ((unsigned)src[e] << 7) | (unsigned)(d & 127);
        }
    }
}

// ---------------- scan bucket totals -> exclusive bucket bases ------------
__global__ void k_scanB(const int* __restrict__ gcur, int* __restrict__ gbase,
                        int* __restrict__ rowptr) {
    __shared__ int s[1024];
    int t = threadIdx.x;
    int v = (t < NBKT) ? gcur[t] : 0;
    s[t] = v;
    __syncthreads();
    for (int d = 1; d < 1024; d <<= 1) {
        int add = (t >= d) ? s[t - d] : 0;
        __syncthreads();
        s[t] += add;
        __syncthreads();
    }
    if (t < NBKT) gbase[t] = s[t] - v;  // exclusive prefix
    if (t == 0) { gbase[NBKT] = NE; rowptr[NN] = NE; }
}

// ---------------- CSR build pass 2: sort bucket in LDS, emit coalesced ----
// csr_off stores BYTE offsets (src*128) of bf16 rows for the aggregate.
__global__ void k_pass2(const unsigned* __restrict__ bbuf, const int* __restrict__ gbase,
                        int* __restrict__ rowptr, float* __restrict__ dis,
                        int* __restrict__ csr_off) {
    __shared__ unsigned vals[BCAP];
    __shared__ int lout[BCAP];
    __shared__ int fh[128], fx[128], fc[128];
    int b = blockIdx.x, t = threadIdx.x;
    int g0 = gbase[b], cnt = gbase[b + 1] - g0;
    const unsigned* in = bbuf + b * BCAP;
    if (t < 128) fh[t] = 0;
    __syncthreads();
    for (int i = t; i < cnt; i += 256) {
        unsigned v = in[i];
        vals[i] = v;
        atomicAdd(&fh[v & 127], 1);
    }
    __syncthreads();
    if (t < 128) fx[t] = fh[t];
    __syncthreads();
    for (int d = 1; d < 128; d <<= 1) {
        int add = (t >= d && t < 128) ? fx[t - d] : 0;
        __syncthreads();
        if (t < 128) fx[t] += add;
        __syncthreads();
    }
    int n = b * 128 + t;
    if (t < 128) {
        int ex = fx[t] - fh[t];     // exclusive within bucket
        fc[t] = ex;
        if (n < NN) {
            rowptr[n] = g0 + ex;
            dis[n] = rsqrtf(1.0f + (float)fh[t]);
        }
    }
    __syncthreads();
    for (int i = t; i < cnt; i += 256) {
        unsigned v = vals[i];
        int p = atomicAdd(&fc[v & 127], 1);
        lout[p] = (int)(v & ~127u);   // src*128 = byte offset of bf16 row
    }
    __syncthreads();
    for (int i = t; i < cnt; i += 256) csr_off[g0 + i] = lout[i];
}

// ---------------- MFMA GEMM: C[N,64] = dis[row] * (A[N,64] @ W[64,64]) ----
__global__ void __launch_bounds__(256) k_gemm_mfma(
        const void* __restrict__ A, int aBase, const void* __restrict__ W,
        bf16* __restrict__ C, const float* __restrict__ dis,
        const int* __restrict__ flag) {
    int f32 = *flag;
    int t = threadIdx.x;
    int lane = t & 63;
    int w = t >> 6;
    int m = lane & 15, q = lane >> 4;

    s8v bh[2][4], bl[2][4];
#pragma unroll
    for (int st = 0; st < 2; st++)
#pragma unroll
        for (int nt = 0; nt < 4; nt++)
#pragma unroll
            for (int j = 0; j < 8; j++) {
                int k = st * 32 + q * 8 + j;
                float wv = ldf(W, k * 64 + nt * 16 + m, f32);
                ushort h = f2b(wv);
                bh[st][nt][j] = (short)h;
                bl[st][nt][j] = (short)f2b(wv - b2f(h));
            }

    ushort* Cu = (ushort*)C;
    int gw = blockIdx.x * 4 + w;
    int nw = gridDim.x * 4;
    for (int mt = gw; mt < NMT; mt += nw) {
        int row = mt * 16 + m;
        s8v ah[2], al[2];
        if (f32) {
            const float* ap = (const float*)A + aBase + row * 64 + q * 8;
#pragma unroll
            for (int st = 0; st < 2; st++)
#pragma unroll
                for (int j = 0; j < 8; j++) {
                    float v = ap[st * 32 + j];
                    ushort h = f2b(v);
                    ah[st][j] = (short)h;
                    al[st][j] = (short)f2b(v - b2f(h));
                }
        } else {
            const short* ap = (const short*)A + aBase + row * 64 + q * 8;
            ah[0] = *(const s8v*)(ap);
            ah[1] = *(const s8v*)(ap + 32);
        }
        float dr[4];
#pragma unroll
        for (int r = 0; r < 4; r++) dr[r] = dis[mt * 16 + q * 4 + r];
#pragma unroll
        for (int nt = 0; nt < 4; nt++) {
            f4v acc = {0.f, 0.f, 0.f, 0.f};
#pragma unroll
            for (int st = 0; st < 2; st++)
                acc = __builtin_amdgcn_mfma_f32_16x16x32_bf16(ah[st], bh[st][nt], acc, 0, 0, 0);
            if (f32) {
#pragma unroll
                for (int st = 0; st < 2; st++) {
                    acc = __builtin_amdgcn_mfma_f32_16x16x32_bf16(ah[st], bl[st][nt], acc, 0, 0, 0);
                    acc = __builtin_amdgcn_mfma_f32_16x16x32_bf16(al[st], bh[st][nt], acc, 0, 0, 0);
                }
            }
            int col = nt * 16 + m;
#pragma unroll
            for (int r = 0; r < 4; r++) {
                int rr = mt * 16 + q * 4 + r;
                Cu[rr * 64 + col] = f2b(dr[r] * acc[r]);
            }
        }
    }
}

// ---------------- fused aggregate + bias + relu ---------------------------
// hs holds PRE-SCALED rows dis[s]*h[s] (bf16). out[n] = relu(dn * (hs[n] +
// sum_edges hs[src]) + b). One wave per node, lane = feature. 16 gathers in
// flight per group; OOB slots hit the zero row at byte offset NN*128.
__global__ void k_aggregate(const bf16* __restrict__ hs, void* hout, int hoBase,
                            const float* __restrict__ dis,
                            const int* __restrict__ rowptr,
                            const int* __restrict__ csr_off,
                            const void* __restrict__ bias,
                            const int* __restrict__ flag) {
    int f32 = *flag;
    int n = blockIdx.x * 4 + (threadIdx.x >> 6);
    int c = threadIdx.x & 63;
    if (n >= NN) return;
    const char* hb = (const char*)hs;
    int c2 = c * 2;
    float dn = dis[n];
    float acc = b2f(*(const ushort*)(hb + n * 128 + c2));   // self: hs[n]
    int j = rowptr[n], end = rowptr[n + 1];
    const int ZOFF = NN * 128;
    while (j < end) {
        int o[16];
#pragma unroll
        for (int k = 0; k < 16; k++) {
            int e = j + k;
            o[k] = (e < end) ? csr_off[e] : ZOFF;
        }
        float v[16];
#pragma unroll
        for (int k = 0; k < 16; k++) v[k] = b2f(*(const ushort*)(hb + o[k] + c2));
#pragma unroll
        for (int k = 0; k < 16; k++) acc += v[k];
        j += 16;
    }
    float r = fmaxf(dn * acc + ldf(bias, c, f32), 0.f);
    stf(hout, hoBase + n * 64 + c, f32, r);
}

// ---------------- head: log_softmax(h2 @ W3 + b3) -------------------------
__global__ void k_head(const void* __restrict__ h2, int hBase,
                       const void* __restrict__ W3, const void* __restrict__ b3,
                       void* out, const int* __restrict__ flag) {
    __shared__ float w[64 * 16];
    __shared__ float hrow[16 * 64];
    int f32 = *flag;
    int t = threadIdx.x;
#pragma unroll
    for (int i = 0; i < 4; i++) w[t + i * 256] = ldf(W3, t + i * 256, f32);
    int r0 = blockIdx.x * 16;
#pragma unroll
    for (int i = 0; i < 4; i++) hrow[t + i * 256] = ldf(h2, hBase + r0 * 64 + t + i * 256, f32);
    __syncthreads();
    int lr = t >> 4, c = t & 15;
    float z = ldf(b3, c, f32);
#pragma unroll
    for (int k = 0; k < 64; k++) z += hrow[lr * 64 + k] * w[k * 16 + c];
    float m = z;
#pragma unroll
    for (int off = 8; off >= 1; off >>= 1) m = fmaxf(m, __shfl_xor(m, off, 16));
    float p = expf(z - m);
    float s = p;
#pragma unroll
    for (int off = 8; off >= 1; off >>= 1) s += __shfl_xor(s, off, 16);
    stf(out, (r0 + lr) * 16 + c, f32, z - m - logf(s));
}

extern "C" void kernel_launch(void* const* d_in, const int* in_sizes, int n_in,
                              void* d_out, int out_size, void* d_ws, size_t ws_size,
                              hipStream_t stream) {
    const void* x  = d_in[0];
    const int* ei  = (const int*)d_in[1];
    const void* W1 = d_in[2];
    const void* b1 = d_in[3];
    const void* W2 = d_in[4];
    const void* b2 = d_in[5];
    const void* W3 = d_in[6];
    const void* b3 = d_in[7];

    // ws layout (4B words):
    //   0       : flag (256)
    //   256     : dis (102400)
    //   102656  : rowptr (102400, NN+1 used)
    //   205056  : gcur (1024, NBKT used)
    //   206080  : gbase (1024, NBKT+1 used)
    //   207104  : csr_off (NE)  -- byte offsets src*128
    //   1807104 : union { bbuf u32[NBKT*BCAP]=3203072 w | bufA bf16[(NN+1)*64]=3200032 w }
    const size_t NEEDED = (size_t)(1807104 + NBKT * BCAP) * 4;  // ~20.05 MB
    if (ws_size < NEEDED) {
        k_sentinel<<<1, 64, 0, stream>>>((unsigned*)d_out);
        return;
    }
    int*      flag    = (int*)d_ws;
    float*    dis     = (float*)d_ws + 256;
    int*      rowptr  = (int*)d_ws + 102656;
    int*      gcur    = (int*)d_ws + 205056;
    int*      gbase   = (int*)d_ws + 206080;
    int*      csr_off = (int*)d_ws + 207104;
    unsigned* bbuf    = (unsigned*)((int*)d_ws + 1807104);
    bf16*     bufA    = (bf16*)bbuf;   // reuses bucket buffer after pass 2

    const int* srcp = ei;
    const int* dstp = ei + NE;
    const int HB = NN * 16;   // h region starts at element NN*16 of d_out

    k_detect<<<1, 256, 0, stream>>>((const unsigned*)x, flag);

    // ---- CSR build: bucket sort (pass1) -> scan -> LDS sort (pass2) ----
    k_zero_i<<<4, 256, 0, stream>>>(gcur, 1024);
    k_pass1<<<NP1, 256, 0, stream>>>(srcp, dstp, gcur, bbuf);
    k_scanB<<<1, 1024, 0, stream>>>(gcur, gbase, rowptr);
    k_pass2<<<NBKT, 256, 0, stream>>>(bbuf, gbase, rowptr, dis, csr_off);
    k_zero_row<<<1, 64, 0, stream>>>(bufA);   // zero gather-target row NN

    // ---- layer 1: h1 = relu(Agg(x @ W1) + b1) ----
    k_gemm_mfma<<<512, 256, 0, stream>>>(x, 0, W1, bufA, dis, flag);
    k_aggregate<<<NN / 4, 256, 0, stream>>>(bufA, d_out, HB, dis, rowptr, csr_off, b1, flag);

    // ---- layer 2: h2 = relu(Agg(h1 @ W2) + b2) ----
    k_gemm_mfma<<<512, 256, 0, stream>>>(d_out, HB, W2, bufA, dis, flag);
    k_aggregate<<<NN / 4, 256, 0, stream>>>(bufA, d_out, HB, dis, rowptr, csr_off, b2, flag);

    // ---- head ----
    k_head<<<NN / 16, 256, 0, stream>>>(d_out, HB, W3, b3, d_out, flag);
}

// Round 10
// 292.243 us; speedup vs baseline: 1.1748x; 1.1748x over previous
//
#include <hip/hip_runtime.h>
#include <hip/hip_bf16.h>

typedef __hip_bfloat16 bf16;
typedef unsigned short ushort;

#define NN 100000
#define NE 1600000
#define NBKT 782      // ceil(NN/128) buckets of 128 dst nodes
#define BCAP 4096     // per-bucket slot capacity (mean 2046, +45 sigma)
#define EPB 8192      // edges per pass-1 block
#define NP1 196       // ceil(NE/EPB)
#define NMT 6250      // NN/16 M-tiles for the MFMA GEMM

typedef __attribute__((ext_vector_type(8))) short s8v;   // 8 bf16 (4 VGPRs)
typedef __attribute__((ext_vector_type(4))) float f4v;   // MFMA C/D

// ---- flag-dispatched load/store: flag==1 -> f32 storage, 0 -> bf16 -------
__device__ __forceinline__ float ldf(const void* p, int i, int f32) {
    return f32 ? ((const float*)p)[i] : __bfloat162float(((const bf16*)p)[i]);
}
__device__ __forceinline__ void stf(void* p, int i, int f32, float v) {
    if (f32) ((float*)p)[i] = v;
    else     ((bf16*)p)[i] = __float2bfloat16(v);
}

// round-to-nearest-even float -> bf16 bits, and back
__device__ __forceinline__ ushort f2b(float f) {
    unsigned u = __builtin_bit_cast(unsigned, f);
    u += 0x7FFF + ((u >> 16) & 1);
    return (ushort)(u >> 16);
}
__device__ __forceinline__ float b2f(ushort h) {
    unsigned u = ((unsigned)h) << 16;
    return __builtin_bit_cast(float, u);
}

// ---- dtype detection on x ~ N(0,1): byte1 of each 32b word --------------
__global__ void k_detect(const unsigned* __restrict__ x, int* __restrict__ flag) {
    __shared__ int cnt[256];
    int t = threadIdx.x, c = 0;
    for (int i = t; i < 2048; i += 256) {
        unsigned e7 = (x[i] >> 8) & 0x7F;
        c += (e7 >= 60 && e7 <= 66) ? 1 : 0;
    }
    cnt[t] = c;
    __syncthreads();
    for (int s = 128; s > 0; s >>= 1) {
        if (t < s) cnt[t] += cnt[t + s];
        __syncthreads();
    }
    if (t == 0) *flag = (cnt[0] >= 1024) ? 0 : 1;  // 1 = float32 tensors
}

__global__ void k_sentinel(unsigned* out) {
    if (threadIdx.x == 0 && blockIdx.x == 0) out[0] = 0x461C461Cu;
}

__global__ void k_zero_i(int* __restrict__ p, int n) {
    int i = blockIdx.x * 256 + threadIdx.x;
    if (i < n) p[i] = 0;
}

// ---------------- CSR build pass 1: bucket edges by dst>>7 ----------------
__global__ void k_pass1(const int* __restrict__ src, const int* __restrict__ dst,
                        int* __restrict__ gcur, unsigned* __restrict__ bbuf) {
    __shared__ int hist[NBKT];
    __shared__ int base[NBKT];
    int t = threadIdx.x;
    int e0 = blockIdx.x * EPB;
    for (int i = t; i < NBKT; i += 256) hist[i] = 0;
    __syncthreads();
    for (int k = 0; k < EPB; k += 256) {
        int e = e0 + k + t;
        if (e < NE) atomicAdd(&hist[dst[e] >> 7], 1);
    }
    __syncthreads();
    for (int i = t; i < NBKT; i += 256) {
        int c = hist[i];
        base[i] = c ? atomicAdd(&gcur[i], c) : 0;
    }
    __syncthreads();
    for (int i = t; i < NBKT; i += 256) hist[i] = 0;  // reuse as local cursor
    __syncthreads();
    for (int k = 0; k < EPB; k += 256) {
        int e = e0 + k + t;
        if (e < NE) {
            int d = dst[e];
            int b = d >> 7;
            int lp = atomicAdd(&hist[b], 1);
            bbuf[b * BCAP + base[b] + lp] = ((unsigned)src[e] << 7) | (unsigned)(d & 127);
        }
    }
}

// ---------------- scan bucket totals -> exclusive bucket bases ------------
__global__ void k_scanB(const int* __restrict__ gcur, int* __restrict__ gbase,
                        int* __restrict__ rowptr) {
    __shared__ int s[1024];
    int t = threadIdx.x;
    int v = (t < NBKT) ? gcur[t] : 0;
    s[t] = v;
    __syncthreads();
    for (int d = 1; d < 1024; d <<= 1) {
        int add = (t >= d) ? s[t - d] : 0;
        __syncthreads();
        s[t] += add;
        __syncthreads();
    }
    if (t < NBKT) gbase[t] = s[t] - v;  // exclusive prefix
    if (t == 0) { gbase[NBKT] = NE; rowptr[NN] = NE; }
}

// ---------------- CSR build pass 2: sort bucket in LDS, emit coalesced ----
// csr_off stores BYTE offsets (src*128) of bf16 rows for the aggregate.
__global__ void k_pass2(const unsigned* __restrict__ bbuf, const int* __restrict__ gbase,
                        int* __restrict__ rowptr, float* __restrict__ dis,
                        int* __restrict__ csr_off) {
    __shared__ unsigned vals[BCAP];
    __shared__ int lout[BCAP];
    __shared__ int fh[128], fx[128], fc[128];
    int b = blockIdx.x, t = threadIdx.x;
    int g0 = gbase[b], cnt = gbase[b + 1] - g0;
    const unsigned* in = bbuf + b * BCAP;
    if (t < 128) fh[t] = 0;
    __syncthreads();
    for (int i = t; i < cnt; i += 256) {
        unsigned v = in[i];
        vals[i] = v;
        atomicAdd(&fh[v & 127], 1);
    }
    __syncthreads();
    if (t < 128) fx[t] = fh[t];
    __syncthreads();
    for (int d = 1; d < 128; d <<= 1) {
        int add = (t >= d && t < 128) ? fx[t - d] : 0;
        __syncthreads();
        if (t < 128) fx[t] += add;
        __syncthreads();
    }
    int n = b * 128 + t;
    if (t < 128) {
        int ex = fx[t] - fh[t];     // exclusive within bucket
        fc[t] = ex;
        if (n < NN) {
            rowptr[n] = g0 + ex;
            dis[n] = rsqrtf(1.0f + (float)fh[t]);
        }
    }
    __syncthreads();
    for (int i = t; i < cnt; i += 256) {
        unsigned v = vals[i];
        int p = atomicAdd(&fc[v & 127], 1);
        lout[p] = (int)(v & ~127u);   // src*128 = byte offset of bf16 row
    }
    __syncthreads();
    for (int i = t; i < cnt; i += 256) csr_off[g0 + i] = lout[i];
}

// ---------------- MFMA GEMM: C[N,64] = dis[row] * (A[N,64] @ W[64,64]) ----
__global__ void __launch_bounds__(256) k_gemm_mfma(
        const void* __restrict__ A, int aBase, const void* __restrict__ W,
        bf16* __restrict__ C, const float* __restrict__ dis,
        const int* __restrict__ flag) {
    int f32 = *flag;
    int t = threadIdx.x;
    int lane = t & 63;
    int w = t >> 6;
    int m = lane & 15, q = lane >> 4;

    s8v bh[2][4], bl[2][4];
#pragma unroll
    for (int st = 0; st < 2; st++)
#pragma unroll
        for (int nt = 0; nt < 4; nt++)
#pragma unroll
            for (int j = 0; j < 8; j++) {
                int k = st * 32 + q * 8 + j;
                float wv = ldf(W, k * 64 + nt * 16 + m, f32);
                ushort h = f2b(wv);
                bh[st][nt][j] = (short)h;
                bl[st][nt][j] = (short)f2b(wv - b2f(h));
            }

    ushort* Cu = (ushort*)C;
    int gw = blockIdx.x * 4 + w;
    int nw = gridDim.x * 4;
    for (int mt = gw; mt < NMT; mt += nw) {
        int row = mt * 16 + m;
        s8v ah[2], al[2];
        if (f32) {
            const float* ap = (const float*)A + aBase + row * 64 + q * 8;
#pragma unroll
            for (int st = 0; st < 2; st++)
#pragma unroll
                for (int j = 0; j < 8; j++) {
                    float v = ap[st * 32 + j];
                    ushort h = f2b(v);
                    ah[st][j] = (short)h;
                    al[st][j] = (short)f2b(v - b2f(h));
                }
        } else {
            const short* ap = (const short*)A + aBase + row * 64 + q * 8;
            ah[0] = *(const s8v*)(ap);
            ah[1] = *(const s8v*)(ap + 32);
        }
        float dr[4];
#pragma unroll
        for (int r = 0; r < 4; r++) dr[r] = dis[mt * 16 + q * 4 + r];
#pragma unroll
        for (int nt = 0; nt < 4; nt++) {
            f4v acc = {0.f, 0.f, 0.f, 0.f};
#pragma unroll
            for (int st = 0; st < 2; st++)
                acc = __builtin_amdgcn_mfma_f32_16x16x32_bf16(ah[st], bh[st][nt], acc, 0, 0, 0);
            if (f32) {
#pragma unroll
                for (int st = 0; st < 2; st++) {
                    acc = __builtin_amdgcn_mfma_f32_16x16x32_bf16(ah[st], bl[st][nt], acc, 0, 0, 0);
                    acc = __builtin_amdgcn_mfma_f32_16x16x32_bf16(al[st], bh[st][nt], acc, 0, 0, 0);
                }
            }
            int col = nt * 16 + m;
#pragma unroll
            for (int r = 0; r < 4; r++) {
                int rr = mt * 16 + q * 4 + r;
                Cu[rr * 64 + col] = f2b(dr[r] * acc[r]);
            }
        }
    }
}

// ---------------- fused aggregate + bias + relu ---------------------------
// hs holds PRE-SCALED rows dis[s]*h[s] (bf16). One wave handles TWO nodes
// (n0,n1), lane = feature: 2 x 16 independent row-gathers in flight per
// group iteration (32 outstanding loads). OOB slots fall back to the node's
// own self row (L1-hot); the exact pad count x self is subtracted at the end.
__global__ void __launch_bounds__(256) k_aggregate(
        const bf16* __restrict__ hs, void* hout, int hoBase,
        const float* __restrict__ dis,
        const int* __restrict__ rowptr,
        const int* __restrict__ csr_off,
        const void* __restrict__ bias,
        const int* __restrict__ flag) {
    int f32 = *flag;
    int pair = blockIdx.x * 4 + (threadIdx.x >> 6);
    int n0 = pair * 2, n1 = n0 + 1;   // NN even; n1 <= NN-1 always
    int c = threadIdx.x & 63;
    if (n0 >= NN) return;
    const char* hb = (const char*)hs;
    int c2 = c * 2;
    float dn0 = dis[n0], dn1 = dis[n1];
    float self0 = b2f(*(const ushort*)(hb + n0 * 128 + c2));
    float self1 = b2f(*(const ushort*)(hb + n1 * 128 + c2));
    int r0 = rowptr[n0], r1 = rowptr[n0 + 1], r2 = rowptr[n1 + 1];
    int j0 = r0, e0 = r1, j1 = r1, e1 = r2;
    int deg0 = e0 - j0, deg1 = e1 - j1;
    const int F0 = n0 * 128, F1 = n1 * 128;   // fallback: own self row
    float acc0 = self0, acc1 = self1;
    int groups = 0;
    while (j0 < e0 || j1 < e1) {
        int o0[16], o1[16];
#pragma unroll
        for (int k = 0; k < 16; k++) o0[k] = (j0 + k < e0) ? csr_off[j0 + k] : F0;
#pragma unroll
        for (int k = 0; k < 16; k++) o1[k] = (j1 + k < e1) ? csr_off[j1 + k] : F1;
        float v0[16], v1[16];
#pragma unroll
        for (int k = 0; k < 16; k++) v0[k] = b2f(*(const ushort*)(hb + o0[k] + c2));
#pragma unroll
        for (int k = 0; k < 16; k++) v1[k] = b2f(*(const ushort*)(hb + o1[k] + c2));
#pragma unroll
        for (int k = 0; k < 16; k++) { acc0 += v0[k]; acc1 += v1[k]; }
        j0 += 16; j1 += 16; groups++;
    }
    // remove the padded self-row contributions (exact counts)
    int pad0 = groups * 16 - deg0;   // >= 0
    int pad1 = groups * 16 - deg1;
    acc0 -= (float)pad0 * self0;
    acc1 -= (float)pad1 * self1;
    float bias0 = ldf(bias, c, f32);
    float out0 = fmaxf(dn0 * acc0 + bias0, 0.f);
    float out1 = fmaxf(dn1 * acc1 + bias0, 0.f);
    stf(hout, hoBase + n0 * 64 + c, f32, out0);
    stf(hout, hoBase + n1 * 64 + c, f32, out1);
}

// ---------------- head: log_softmax(h2 @ W3 + b3) -------------------------
__global__ void k_head(const void* __restrict__ h2, int hBase,
                       const void* __restrict__ W3, const void* __restrict__ b3,
                       void* out, const int* __restrict__ flag) {
    __shared__ float w[64 * 16];
    __shared__ float hrow[16 * 64];
    int f32 = *flag;
    int t = threadIdx.x;
#pragma unroll
    for (int i = 0; i < 4; i++) w[t + i * 256] = ldf(W3, t + i * 256, f32);
    int r0 = blockIdx.x * 16;
#pragma unroll
    for (int i = 0; i < 4; i++) hrow[t + i * 256] = ldf(h2, hBase + r0 * 64 + t + i * 256, f32);
    __syncthreads();
    int lr = t >> 4, c = t & 15;
    float z = ldf(b3, c, f32);
#pragma unroll
    for (int k = 0; k < 64; k++) z += hrow[lr * 64 + k] * w[k * 16 + c];
    float m = z;
#pragma unroll
    for (int off = 8; off >= 1; off >>= 1) m = fmaxf(m, __shfl_xor(m, off, 16));
    float p = expf(z - m);
    float s = p;
#pragma unroll
    for (int off = 8; off >= 1; off >>= 1) s += __shfl_xor(s, off, 16);
    stf(out, (r0 + lr) * 16 + c, f32, z - m - logf(s));
}

extern "C" void kernel_launch(void* const* d_in, const int* in_sizes, int n_in,
                              void* d_out, int out_size, void* d_ws, size_t ws_size,
                              hipStream_t stream) {
    const void* x  = d_in[0];
    const int* ei  = (const int*)d_in[1];
    const void* W1 = d_in[2];
    const void* b1 = d_in[3];
    const void* W2 = d_in[4];
    const void* b2 = d_in[5];
    const void* W3 = d_in[6];
    const void* b3 = d_in[7];

    // ws layout (4B words):
    //   0       : flag (256)
    //   256     : dis (102400)
    //   102656  : rowptr (102400, NN+1 used)
    //   205056  : gcur (1024, NBKT used)
    //   206080  : gbase (1024, NBKT+1 used)
    //   207104  : csr_off (NE)  -- byte offsets src*128
    //   1807104 : union { bbuf u32[NBKT*BCAP]=3203072 w | bufA bf16[NN*64]=3200000 w }
    const size_t NEEDED = (size_t)(1807104 + NBKT * BCAP) * 4;  // ~20.05 MB
    if (ws_size < NEEDED) {
        k_sentinel<<<1, 64, 0, stream>>>((unsigned*)d_out);
        return;
    }
    int*      flag    = (int*)d_ws;
    float*    dis     = (float*)d_ws + 256;
    int*      rowptr  = (int*)d_ws + 102656;
    int*      gcur    = (int*)d_ws + 205056;
    int*      gbase   = (int*)d_ws + 206080;
    int*      csr_off = (int*)d_ws + 207104;
    unsigned* bbuf    = (unsigned*)((int*)d_ws + 1807104);
    bf16*     bufA    = (bf16*)bbuf;   // reuses bucket buffer after pass 2

    const int* srcp = ei;
    const int* dstp = ei + NE;
    const int HB = NN * 16;   // h region starts at element NN*16 of d_out

    k_detect<<<1, 256, 0, stream>>>((const unsigned*)x, flag);

    // ---- CSR build: bucket sort (pass1) -> scan -> LDS sort (pass2) ----
    k_zero_i<<<4, 256, 0, stream>>>(gcur, 1024);
    k_pass1<<<NP1, 256, 0, stream>>>(srcp, dstp, gcur, bbuf);
    k_scanB<<<1, 1024, 0, stream>>>(gcur, gbase, rowptr);
    k_pass2<<<NBKT, 256, 0, stream>>>(bbuf, gbase, rowptr, dis, csr_off);

    // ---- layer 1: h1 = relu(Agg(x @ W1) + b1) ----
    k_gemm_mfma<<<512, 256, 0, stream>>>(x, 0, W1, bufA, dis, flag);
    k_aggregate<<<NN / 8, 256, 0, stream>>>(bufA, d_out, HB, dis, rowptr, csr_off, b1, flag);

    // ---- layer 2: h2 = relu(Agg(h1 @ W2) + b2) ----
    k_gemm_mfma<<<512, 256, 0, stream>>>(d_out, HB, W2, bufA, dis, flag);
    k_aggregate<<<NN / 8, 256, 0, stream>>>(bufA, d_out, HB, dis, rowptr, csr_off, b2, flag);

    // ---- head ----
    k_head<<<NN / 16, 256, 0, stream>>>(d_out, HB, W3, b3, d_out, flag);
}

// Round 11
// 288.625 us; speedup vs baseline: 1.1896x; 1.0125x over previous
//
#include <hip/hip_runtime.h>
#include <hip/hip_bf16.h>

typedef __hip_bfloat16 bf16;
typedef unsigned short ushort;

#define NN 100000
#define NE 1600000
#define NBKT 782      // ceil(NN/128) buckets of 128 dst nodes
#define BCAP 4096     // per-bucket slot capacity (mean 2046, +45 sigma)
#define EPB 8192      // edges per pass-1 block
#define NP1 196       // ceil(NE/EPB)
#define NMT 6250      // NN/16 M-tiles for the MFMA GEMM

typedef __attribute__((ext_vector_type(8))) short s8v;   // 8 bf16 (4 VGPRs)
typedef __attribute__((ext_vector_type(4))) float f4v;   // MFMA C/D

// ---- flag-dispatched load/store: flag==1 -> f32 storage, 0 -> bf16 -------
__device__ __forceinline__ float ldf(const void* p, int i, int f32) {
    return f32 ? ((const float*)p)[i] : __bfloat162float(((const bf16*)p)[i]);
}
__device__ __forceinline__ void stf(void* p, int i, int f32, float v) {
    if (f32) ((float*)p)[i] = v;
    else     ((bf16*)p)[i] = __float2bfloat16(v);
}

// round-to-nearest-even float -> bf16 bits, and back
__device__ __forceinline__ ushort f2b(float f) {
    unsigned u = __builtin_bit_cast(unsigned, f);
    u += 0x7FFF + ((u >> 16) & 1);
    return (ushort)(u >> 16);
}
__device__ __forceinline__ float b2f(ushort h) {
    unsigned u = ((unsigned)h) << 16;
    return __builtin_bit_cast(float, u);
}

// ---- dtype detection on x ~ N(0,1) + zero gcur (merged launch) ----------
__global__ void k_detect(const unsigned* __restrict__ x, int* __restrict__ flag,
                         int* __restrict__ gcur) {
    int gi = blockIdx.x * 256 + threadIdx.x;
    if (gi < 1024) gcur[gi] = 0;
    if (blockIdx.x != 0) return;
    __shared__ int cnt[256];
    int t = threadIdx.x, c = 0;
    for (int i = t; i < 2048; i += 256) {
        unsigned e7 = (x[i] >> 8) & 0x7F;
        c += (e7 >= 60 && e7 <= 66) ? 1 : 0;
    }
    cnt[t] = c;
    __syncthreads();
    for (int s = 128; s > 0; s >>= 1) {
        if (t < s) cnt[t] += cnt[t + s];
        __syncthreads();
    }
    if (t == 0) *flag = (cnt[0] >= 1024) ? 0 : 1;  // 1 = float32 tensors
}

__global__ void k_sentinel(unsigned* out) {
    if (threadIdx.x == 0 && blockIdx.x == 0) out[0] = 0x461C461Cu;
}

// ---------------- CSR build pass 1: bucket edges by dst>>7 ----------------
__global__ void k_pass1(const int* __restrict__ src, const int* __restrict__ dst,
                        int* __restrict__ gcur, unsigned* __restrict__ bbuf) {
    __shared__ int hist[NBKT];
    __shared__ int base[NBKT];
    int t = threadIdx.x;
    int e0 = blockIdx.x * EPB;
    for (int i = t; i < NBKT; i += 256) hist[i] = 0;
    __syncthreads();
    for (int k = 0; k < EPB; k += 256) {
        int e = e0 + k + t;
        if (e < NE) atomicAdd(&hist[dst[e] >> 7], 1);
    }
    __syncthreads();
    for (int i = t; i < NBKT; i += 256) {
        int c = hist[i];
        base[i] = c ? atomicAdd(&gcur[i], c) : 0;
    }
    __syncthreads();
    for (int i = t; i < NBKT; i += 256) hist[i] = 0;  // reuse as local cursor
    __syncthreads();
    for (int k = 0; k < EPB; k += 256) {
        int e = e0 + k + t;
        if (e < NE) {
            int d = dst[e];
            int b = d >> 7;
            int lp = atomicAdd(&hist[b], 1);
            bbuf[b * BCAP + base[b] + lp] = ((unsigned)src[e] << 7) | (unsigned)(d & 127);
        }
    }
}

// ---------------- scan bucket totals -> exclusive bucket bases ------------
__global__ void k_scanB(const int* __restrict__ gcur, int* __restrict__ gbase,
                        int* __restrict__ rowptr) {
    __shared__ int s[1024];
    int t = threadIdx.x;
    int v = (t < NBKT) ? gcur[t] : 0;
    s[t] = v;
    __syncthreads();
    for (int d = 1; d < 1024; d <<= 1) {
        int add = (t >= d) ? s[t - d] : 0;
        __syncthreads();
        s[t] += add;
        __syncthreads();
    }
    if (t < NBKT) gbase[t] = s[t] - v;  // exclusive prefix
    if (t == 0) { gbase[NBKT] = NE; rowptr[NN] = NE; }
}

// ---------------- CSR build pass 2: sort bucket in LDS, emit coalesced ----
// csr_off stores BYTE offsets (src*128) of bf16 rows for the aggregate.
__global__ void k_pass2(const unsigned* __restrict__ bbuf, const int* __restrict__ gbase,
                        int* __restrict__ rowptr, float* __restrict__ dis,
                        int* __restrict__ csr_off) {
    __shared__ unsigned vals[BCAP];
    __shared__ int lout[BCAP];
    __shared__ int fh[128], fx[128], fc[128];
    int b = blockIdx.x, t = threadIdx.x;
    int g0 = gbase[b], cnt = gbase[b + 1] - g0;
    const unsigned* in = bbuf + b * BCAP;
    if (t < 128) fh[t] = 0;
    __syncthreads();
    for (int i = t; i < cnt; i += 256) {
        unsigned v = in[i];
        vals[i] = v;
        atomicAdd(&fh[v & 127], 1);
    }
    __syncthreads();
    if (t < 128) fx[t] = fh[t];
    __syncthreads();
    for (int d = 1; d < 128; d <<= 1) {
        int add = (t >= d && t < 128) ? fx[t - d] : 0;
        __syncthreads();
        if (t < 128) fx[t] += add;
        __syncthreads();
    }
    int n = b * 128 + t;
    if (t < 128) {
        int ex = fx[t] - fh[t];     // exclusive within bucket
        fc[t] = ex;
        if (n < NN) {
            rowptr[n] = g0 + ex;
            dis[n] = rsqrtf(1.0f + (float)fh[t]);
        }
    }
    __syncthreads();
    for (int i = t; i < cnt; i += 256) {
        unsigned v = vals[i];
        int p = atomicAdd(&fc[v & 127], 1);
        lout[p] = (int)(v & ~127u);   // src*128 = byte offset of bf16 row
    }
    __syncthreads();
    for (int i = t; i < cnt; i += 256) csr_off[g0 + i] = lout[i];
}

// ---------------- MFMA GEMM: C[N,64] = dis[row] * (A[N,64] @ W[64,64]) ----
__global__ void __launch_bounds__(256) k_gemm_mfma(
        const void* __restrict__ A, int aBase, const void* __restrict__ W,
        bf16* __restrict__ C, const float* __restrict__ dis,
        const int* __restrict__ flag) {
    int f32 = *flag;
    int t = threadIdx.x;
    int lane = t & 63;
    int w = t >> 6;
    int m = lane & 15, q = lane >> 4;

    s8v bh[2][4], bl[2][4];
#pragma unroll
    for (int st = 0; st < 2; st++)
#pragma unroll
        for (int nt = 0; nt < 4; nt++)
#pragma unroll
            for (int j = 0; j < 8; j++) {
                int k = st * 32 + q * 8 + j;
                float wv = ldf(W, k * 64 + nt * 16 + m, f32);
                ushort h = f2b(wv);
                bh[st][nt][j] = (short)h;
                bl[st][nt][j] = (short)f2b(wv - b2f(h));
            }

    ushort* Cu = (ushort*)C;
    int gw = blockIdx.x * 4 + w;
    int nw = gridDim.x * 4;
    for (int mt = gw; mt < NMT; mt += nw) {
        int row = mt * 16 + m;
        s8v ah[2], al[2];
        if (f32) {
            const float* ap = (const float*)A + aBase + row * 64 + q * 8;
#pragma unroll
            for (int st = 0; st < 2; st++)
#pragma unroll
                for (int j = 0; j < 8; j++) {
                    float v = ap[st * 32 + j];
                    ushort h = f2b(v);
                    ah[st][j] = (short)h;
                    al[st][j] = (short)f2b(v - b2f(h));
                }
        } else {
            const short* ap = (const short*)A + aBase + row * 64 + q * 8;
            ah[0] = *(const s8v*)(ap);
            ah[1] = *(const s8v*)(ap + 32);
        }
        float dr[4];
#pragma unroll
        for (int r = 0; r < 4; r++) dr[r] = dis[mt * 16 + q * 4 + r];
#pragma unroll
        for (int nt = 0; nt < 4; nt++) {
            f4v acc = {0.f, 0.f, 0.f, 0.f};
#pragma unroll
            for (int st = 0; st < 2; st++)
                acc = __builtin_amdgcn_mfma_f32_16x16x32_bf16(ah[st], bh[st][nt], acc, 0, 0, 0);
            if (f32) {
#pragma unroll
                for (int st = 0; st < 2; st++) {
                    acc = __builtin_amdgcn_mfma_f32_16x16x32_bf16(ah[st], bl[st][nt], acc, 0, 0, 0);
                    acc = __builtin_amdgcn_mfma_f32_16x16x32_bf16(al[st], bh[st][nt], acc, 0, 0, 0);
                }
            }
            int col = nt * 16 + m;
#pragma unroll
            for (int r = 0; r < 4; r++) {
                int rr = mt * 16 + q * 4 + r;
                Cu[rr * 64 + col] = f2b(dr[r] * acc[r]);
            }
        }
    }
}

// ---------------- fused aggregate + bias + relu ---------------------------
// hs holds PRE-SCALED rows dis[s]*h[s] (bf16). One wave handles TWO nodes
// (n0,n1), lane = feature: 2 x 16 independent row-gathers in flight per
// group iteration. __launch_bounds__(256,4) raises the VGPR cap to 128 so
// the offset+value arrays stay in registers and all 32 gathers issue before
// the first vmcnt wait (round-10 VGPR=48 showed the compiler serialized).
__global__ void __launch_bounds__(256, 4) k_aggregate(
        const bf16* __restrict__ hs, void* hout, int hoBase,
        const float* __restrict__ dis,
        const int* __restrict__ rowptr,
        const int* __restrict__ csr_off,
        const void* __restrict__ bias,
        const int* __restrict__ flag) {
    int f32 = *flag;
    int pair = blockIdx.x * 4 + (threadIdx.x >> 6);
    int n0 = pair * 2, n1 = n0 + 1;   // NN even; n1 <= NN-1 always
    int c = threadIdx.x & 63;
    if (n0 >= NN) return;
    const char* hb = (const char*)hs;
    int c2 = c * 2;
    float dn0 = dis[n0], dn1 = dis[n1];
    float self0 = b2f(*(const ushort*)(hb + n0 * 128 + c2));
    float self1 = b2f(*(const ushort*)(hb + n1 * 128 + c2));
    int r0 = rowptr[n0], r1 = rowptr[n0 + 1], r2 = rowptr[n1 + 1];
    int j0 = r0, e0 = r1, j1 = r1, e1 = r2;
    int deg0 = e0 - j0, deg1 = e1 - j1;
    const int F0 = n0 * 128, F1 = n1 * 128;   // fallback: own self row
    float acc0 = self0, acc1 = self1;
    int groups = 0;
    while (j0 < e0 || j1 < e1) {
        int o0[16], o1[16];
#pragma unroll
        for (int k = 0; k < 16; k++) o0[k] = (j0 + k < e0) ? csr_off[j0 + k] : F0;
#pragma unroll
        for (int k = 0; k < 16; k++) o1[k] = (j1 + k < e1) ? csr_off[j1 + k] : F1;
        float v0[16], v1[16];
#pragma unroll
        for (int k = 0; k < 16; k++) v0[k] = b2f(*(const ushort*)(hb + o0[k] + c2));
#pragma unroll
        for (int k = 0; k < 16; k++) v1[k] = b2f(*(const ushort*)(hb + o1[k] + c2));
#pragma unroll
        for (int k = 0; k < 16; k++) { acc0 += v0[k]; acc1 += v1[k]; }
        j0 += 16; j1 += 16; groups++;
    }
    // remove the padded self-row contributions (exact counts)
    int pad0 = groups * 16 - deg0;   // >= 0
    int pad1 = groups * 16 - deg1;
    acc0 -= (float)pad0 * self0;
    acc1 -= (float)pad1 * self1;
    float bias0 = ldf(bias, c, f32);
    float out0 = fmaxf(dn0 * acc0 + bias0, 0.f);
    float out1 = fmaxf(dn1 * acc1 + bias0, 0.f);
    stf(hout, hoBase + n0 * 64 + c, f32, out0);
    stf(hout, hoBase + n1 * 64 + c, f32, out1);
}

// ---------------- head: log_softmax(h2 @ W3 + b3) -------------------------
__global__ void k_head(const void* __restrict__ h2, int hBase,
                       const void* __restrict__ W3, const void* __restrict__ b3,
                       void* out, const int* __restrict__ flag) {
    __shared__ float w[64 * 16];
    __shared__ float hrow[16 * 64];
    int f32 = *flag;
    int t = threadIdx.x;
#pragma unroll
    for (int i = 0; i < 4; i++) w[t + i * 256] = ldf(W3, t + i * 256, f32);
    int r0 = blockIdx.x * 16;
#pragma unroll
    for (int i = 0; i < 4; i++) hrow[t + i * 256] = ldf(h2, hBase + r0 * 64 + t + i * 256, f32);
    __syncthreads();
    int lr = t >> 4, c = t & 15;
    float z = ldf(b3, c, f32);
#pragma unroll
    for (int k = 0; k < 64; k++) z += hrow[lr * 64 + k] * w[k * 16 + c];
    float m = z;
#pragma unroll
    for (int off = 8; off >= 1; off >>= 1) m = fmaxf(m, __shfl_xor(m, off, 16));
    float p = expf(z - m);
    float s = p;
#pragma unroll
    for (int off = 8; off >= 1; off >>= 1) s += __shfl_xor(s, off, 16);
    stf(out, (r0 + lr) * 16 + c, f32, z - m - logf(s));
}

extern "C" void kernel_launch(void* const* d_in, const int* in_sizes, int n_in,
                              void* d_out, int out_size, void* d_ws, size_t ws_size,
                              hipStream_t stream) {
    const void* x  = d_in[0];
    const int* ei  = (const int*)d_in[1];
    const void* W1 = d_in[2];
    const void* b1 = d_in[3];
    const void* W2 = d_in[4];
    const void* b2 = d_in[5];
    const void* W3 = d_in[6];
    const void* b3 = d_in[7];

    // ws layout (4B words):
    //   0       : flag (256)
    //   256     : dis (102400)
    //   102656  : rowptr (102400, NN+1 used)
    //   205056  : gcur (1024, NBKT used)
    //   206080  : gbase (1024, NBKT+1 used)
    //   207104  : csr_off (NE)  -- byte offsets src*128
    //   1807104 : union { bbuf u32[NBKT*BCAP]=3203072 w | bufA bf16[NN*64]=3200000 w }
    const size_t NEEDED = (size_t)(1807104 + NBKT * BCAP) * 4;  // ~20.05 MB
    if (ws_size < NEEDED) {
        k_sentinel<<<1, 64, 0, stream>>>((unsigned*)d_out);
        return;
    }
    int*      flag    = (int*)d_ws;
    float*    dis     = (float*)d_ws + 256;
    int*      rowptr  = (int*)d_ws + 102656;
    int*      gcur    = (int*)d_ws + 205056;
    int*      gbase   = (int*)d_ws + 206080;
    int*      csr_off = (int*)d_ws + 207104;
    unsigned* bbuf    = (unsigned*)((int*)d_ws + 1807104);
    bf16*     bufA    = (bf16*)bbuf;   // reuses bucket buffer after pass 2

    const int* srcp = ei;
    const int* dstp = ei + NE;
    const int HB = NN * 16;   // h region starts at element NN*16 of d_out

    // ---- detect dtype + zero gcur (merged) ----
    k_detect<<<4, 256, 0, stream>>>((const unsigned*)x, flag, gcur);

    // ---- CSR build: bucket sort (pass1) -> scan -> LDS sort (pass2) ----
    k_pass1<<<NP1, 256, 0, stream>>>(srcp, dstp, gcur, bbuf);
    k_scanB<<<1, 1024, 0, stream>>>(gcur, gbase, rowptr);
    k_pass2<<<NBKT, 256, 0, stream>>>(bbuf, gbase, rowptr, dis, csr_off);

    // ---- layer 1: h1 = relu(Agg(x @ W1) + b1) ----
    k_gemm_mfma<<<512, 256, 0, stream>>>(x, 0, W1, bufA, dis, flag);
    k_aggregate<<<NN / 8, 256, 0, stream>>>(bufA, d_out, HB, dis, rowptr, csr_off, b1, flag);

    // ---- layer 2: h2 = relu(Agg(h1 @ W2) + b2) ----
    k_gemm_mfma<<<512, 256, 0, stream>>>(d_out, HB, W2, bufA, dis, flag);
    k_aggregate<<<NN / 8, 256, 0, stream>>>(bufA, d_out, HB, dis, rowptr, csr_off, b2, flag);

    // ---- head ----
    k_head<<<NN / 16, 256, 0, stream>>>(d_out, HB, W3, b3, d_out, flag);
}